// Round 6
// baseline (163.304 us; speedup 1.0000x reference)
//
#include <hip/hip_runtime.h>
#include <math.h>

#define N_ROWS 262144
#define DIM 64
#define K_CODES 1024
#define NT 64                 // code tiles of 16
#define ROWS_PER_BLOCK 256
#define EPSF 1e-12f

typedef _Float16 f16x8 __attribute__((ext_vector_type(8)));
typedef float f32x4 __attribute__((ext_vector_type(4)));

// ws layout (floats):
//   wn      : [0, 65536)         normalized codebook fp32 (for gather/epilogue)
//   msw     : [65536, 66560)     -0.5 * sum(wn^2) per code
//   partial : [66560, 67584)     per-block loss partials (1024)
//   wf      : halves after that  codebook hi/lo f16, 16x16x32 B-fragment order
//             per tile t (16 codes): 2048 halves = 256 f16x8 units:
//               [0,64)=hi s0  [64,128)=hi s1  [128,192)=lo s0  [192,256)=lo s1
//             unit index within block: lane (= g*16 + code%16), elem i
//             +1 guard tile so the main loop can prefetch unconditionally.

__global__ __launch_bounds__(64) void prep_codebook(
    const float* __restrict__ w, float* __restrict__ wn,
    float* __restrict__ msw, _Float16* __restrict__ wf)
{
    int k = blockIdx.x;
    int d = threadIdx.x;
    float v = w[k * DIM + d];
    float sq = v * v;
    #pragma unroll
    for (int off = 32; off; off >>= 1) sq += __shfl_xor(sq, off, 64);
    float n = fmaxf(sqrtf(sq), EPSF);
    float o = v / n;
    wn[k * DIM + d] = o;
    float s2 = o * o;
    #pragma unroll
    for (int off = 32; off; off >>= 1) s2 += __shfl_xor(s2, off, 64);
    if (d == 0) msw[k] = -0.5f * s2;

    _Float16 hi = (_Float16)o;
    _Float16 lo = (_Float16)(o - (float)hi);
    // B fragment for 16x16x32: lane = g*16 + n holds k-dims s*32 + g*8 + i
    int t = k >> 4, nn = k & 15;
    int s = d >> 5, ks = d & 31, g = ks >> 3, i = ks & 7;
    int lane = g * 16 + nn;
    size_t base = (size_t)t * 2048 + (size_t)s * 512 + (size_t)lane * 8 + i;
    wf[base] = hi;            // h = 0
    wf[base + 1024] = lo;     // h = 1
}

__global__ __launch_bounds__(256, 3) void vq_main_kernel(
    const float* __restrict__ x,
    const float* __restrict__ wn,
    const float* __restrict__ msw,
    const _Float16* __restrict__ wf,
    float* __restrict__ out_q,
    float* __restrict__ out_idx,
    float* __restrict__ partial)
{
    __shared__ int idx_lds[ROWS_PER_BLOCK];
    __shared__ float inv_lds[ROWS_PER_BLOCK];
    __shared__ float red[4];

    const int tid = threadIdx.x;
    const int wv = tid >> 6;
    const int lane = tid & 63;
    const int nidx = lane & 15;       // code-within-tile / x-row-within-rowtile
    const int g = lane >> 4;          // k-group
    const int block_row0 = blockIdx.x * ROWS_PER_BLOCK;

    // ---- prologue: 64 rows/wave (4 row-tiles of 16), normalize, hi/lo A-frags ----
    // A for 16x16x32: lane = g*16+m holds A[m][k = g*8+i] (+s*32 per kstep)
    f16x8 ah[4][2], al[4][2];
    #pragma unroll
    for (int rt = 0; rt < 4; ++rt) {
        const int arow = block_row0 + wv * 64 + rt * 16 + nidx;
        const float* xrow = x + (size_t)arow * DIM + g * 8;
        float xv[2][8];
        #pragma unroll
        for (int s = 0; s < 2; ++s) {
            float4 q0 = *(const float4*)(xrow + s * 32);
            float4 q1 = *(const float4*)(xrow + s * 32 + 4);
            xv[s][0] = q0.x; xv[s][1] = q0.y; xv[s][2] = q0.z; xv[s][3] = q0.w;
            xv[s][4] = q1.x; xv[s][5] = q1.y; xv[s][6] = q1.z; xv[s][7] = q1.w;
        }
        float ss = 0.f;
        #pragma unroll
        for (int s = 0; s < 2; ++s)
            #pragma unroll
            for (int i = 0; i < 8; ++i) ss += xv[s][i] * xv[s][i];
        ss += __shfl_xor(ss, 16, 64);  // sum across the 4 k-groups holding this row
        ss += __shfl_xor(ss, 32, 64);
        float nrm = fmaxf(sqrtf(ss), EPSF);
        float inv = 1.0f / nrm;
        if (g == 0) inv_lds[wv * 64 + rt * 16 + nidx] = inv;
        #pragma unroll
        for (int s = 0; s < 2; ++s)
            #pragma unroll
            for (int i = 0; i < 8; ++i) {
                float v = xv[s][i] * inv;
                _Float16 hi = (_Float16)v;
                ah[rt][s][i] = hi;
                al[rt][s][i] = (_Float16)(v - (float)hi);
            }
    }

    float best[4][4];
    int bt[4][4];
    #pragma unroll
    for (int rt = 0; rt < 4; ++rt)
        #pragma unroll
        for (int r = 0; r < 4; ++r) { best[rt][r] = -3.4e38f; bt[rt][r] = 0; }

    // ---- main loop: 64 code tiles, NO barriers, depth-1 prefetch ----
    const f16x8* wf8 = (const f16x8*)wf;
    f16x8 cb0 = wf8[lane];
    f16x8 cb1 = wf8[64 + lane];
    f16x8 cb2 = wf8[128 + lane];
    f16x8 cb3 = wf8[192 + lane];
    float mval = msw[nidx];

    for (int t = 0; t < NT; ++t) {
        // prefetch tile t+1 (guard tile makes t=NT-1 safe; values unused)
        const f16x8* np = wf8 + (size_t)(t + 1) * 256;
        f16x8 nb0 = np[lane];
        f16x8 nb1 = np[64 + lane];
        f16x8 nb2 = np[128 + lane];
        f16x8 nb3 = np[192 + lane];
        float nmval = msw[(t + 1) * 16 + nidx];

        f32x4 acc[4];
        #pragma unroll
        for (int rt = 0; rt < 4; ++rt) {
            acc[rt][0] = mval; acc[rt][1] = mval;
            acc[rt][2] = mval; acc[rt][3] = mval;
        }
        // 24 MFMA: 4 independent chains (one per row-tile), depth 6
        #pragma unroll
        for (int rt = 0; rt < 4; ++rt)
            acc[rt] = __builtin_amdgcn_mfma_f32_16x16x32_f16(ah[rt][0], cb0, acc[rt], 0, 0, 0);
        #pragma unroll
        for (int rt = 0; rt < 4; ++rt)
            acc[rt] = __builtin_amdgcn_mfma_f32_16x16x32_f16(ah[rt][1], cb1, acc[rt], 0, 0, 0);
        #pragma unroll
        for (int rt = 0; rt < 4; ++rt)
            acc[rt] = __builtin_amdgcn_mfma_f32_16x16x32_f16(al[rt][0], cb0, acc[rt], 0, 0, 0);
        #pragma unroll
        for (int rt = 0; rt < 4; ++rt)
            acc[rt] = __builtin_amdgcn_mfma_f32_16x16x32_f16(al[rt][1], cb1, acc[rt], 0, 0, 0);
        #pragma unroll
        for (int rt = 0; rt < 4; ++rt)
            acc[rt] = __builtin_amdgcn_mfma_f32_16x16x32_f16(ah[rt][0], cb2, acc[rt], 0, 0, 0);
        #pragma unroll
        for (int rt = 0; rt < 4; ++rt)
            acc[rt] = __builtin_amdgcn_mfma_f32_16x16x32_f16(ah[rt][1], cb3, acc[rt], 0, 0, 0);

        #pragma unroll
        for (int rt = 0; rt < 4; ++rt)
            #pragma unroll
            for (int r = 0; r < 4; ++r)
                if (acc[rt][r] > best[rt][r]) { best[rt][r] = acc[rt][r]; bt[rt][r] = t; }

        cb0 = nb0; cb1 = nb1; cb2 = nb2; cb3 = nb3; mval = nmval;
    }

    // ---- argmax reduce across the 16 lanes holding each row ----
    // C 16x16: col = lane&15 (code), row = (lane>>4)*4 + r (x-row within rt)
    #pragma unroll
    for (int rt = 0; rt < 4; ++rt)
        #pragma unroll
        for (int r = 0; r < 4; ++r) {
            float b = best[rt][r];
            int bi = bt[rt][r] * 16 + nidx;
            #pragma unroll
            for (int off = 1; off <= 8; off <<= 1) {
                float ob = __shfl_xor(b, off, 64);
                int oi = __shfl_xor(bi, off, 64);
                if (ob > b || (ob == b && oi < bi)) { b = ob; bi = oi; }
            }
            if (nidx == 0)
                idx_lds[wv * 64 + rt * 16 + g * 4 + r] = bi;
        }
    __syncthreads();

    // ---- epilogue: gather fp32 codebook rows, write out, loss partial ----
    float ls = 0.f;
    #pragma unroll
    for (int rep = 0; rep < 2; ++rep) {
        const int lr = rep * 128 + (tid >> 1);
        const int grow = block_row0 + lr;
        const int d0 = (tid & 1) * 32;
        const int ci = idx_lds[lr];
        const float invn = inv_lds[lr];
        const float4* xp = (const float4*)(x + (size_t)grow * DIM + d0);
        const float4* qp = (const float4*)(wn + (size_t)ci * DIM + d0);
        float4* op = (float4*)(out_q + (size_t)grow * DIM + d0);
        #pragma unroll
        for (int i = 0; i < 8; ++i) {
            float4 qv = qp[i];
            float4 xv4 = xp[i];
            float e0 = qv.x - xv4.x * invn;
            float e1 = qv.y - xv4.y * invn;
            float e2 = qv.z - xv4.z * invn;
            float e3 = qv.w - xv4.w * invn;
            ls += e0 * e0 + e1 * e1 + e2 * e2 + e3 * e3;
            op[i] = qv;
        }
        if (!(tid & 1)) out_idx[grow] = (float)ci;
    }

    float s = ls;
    #pragma unroll
    for (int off = 32; off; off >>= 1) s += __shfl_xor(s, off, 64);
    if (lane == 0) red[wv] = s;
    __syncthreads();
    if (tid == 0) partial[blockIdx.x] = (red[0] + red[1]) + (red[2] + red[3]);
}

__global__ __launch_bounds__(256) void finalize_kernel(
    const float* __restrict__ partial, float* __restrict__ loss_out)
{
    __shared__ float red[4];
    int t = threadIdx.x;
    float s = 0.f;
    #pragma unroll
    for (int i = 0; i < 4; ++i) s += partial[t * 4 + i];  // fixed order
    #pragma unroll
    for (int off = 32; off; off >>= 1) s += __shfl_xor(s, off, 64);
    if ((t & 63) == 0) red[t >> 6] = s;
    __syncthreads();
    if (t == 0)
        *loss_out = 1.25f * (((red[0] + red[1]) + (red[2] + red[3]))
                             / (float)((size_t)N_ROWS * DIM));
}

extern "C" void kernel_launch(void* const* d_in, const int* in_sizes, int n_in,
                              void* d_out, int out_size, void* d_ws, size_t ws_size,
                              hipStream_t stream) {
    const float* x = (const float*)d_in[0];   // [N, D]
    const float* w = (const float*)d_in[1];   // [K, D]
    float* out = (float*)d_out;
    float* ws = (float*)d_ws;

    float* wn      = ws;                                   // 65536 floats
    float* msw     = wn + (size_t)K_CODES * DIM;           // 1024 floats
    float* partial = msw + K_CODES;                        // 1024 floats
    _Float16* wf   = (_Float16*)(partial + 1024);          // 65*2048 halves (incl. guard)

    float* out_q    = out;                                 // [N*D]
    float* out_loss = out + (size_t)N_ROWS * DIM;          // [1]
    float* out_idx  = out_loss + 1;                        // [N]

    prep_codebook<<<K_CODES, 64, 0, stream>>>(w, wn, msw, wf);
    vq_main_kernel<<<N_ROWS / ROWS_PER_BLOCK, 256, 0, stream>>>(
        x, wn, msw, wf, out_q, out_idx, partial);
    finalize_kernel<<<1, 256, 0, stream>>>(partial, out_loss);
}

// Round 7
// 124.249 us; speedup vs baseline: 1.3143x; 1.3143x over previous
//
#include <hip/hip_runtime.h>
#include <math.h>

#define N_ROWS 262144
#define DIM 64
#define K_CODES 1024
#define NT 64                 // code tiles of 16
#define ROWS_PER_BLOCK 128
#define EPSF 1e-12f

typedef _Float16 f16x8 __attribute__((ext_vector_type(8)));
typedef float f32x4 __attribute__((ext_vector_type(4)));

// ws layout (floats):
//   wn      : [0, 65536)         normalized codebook fp32 (gather/epilogue)
//   msw     : [65536, 66560)     -0.5 * sum(wn^2) per code
//   partial : [66560, 68608)     per-block loss partials (2048)
//   wf      : halves after that  codebook hi/lo f16, 16x16x32 B-fragment order
//             per 16-code tile t: 2048 halves:
//               [0,512)=hi s0  [512,1024)=hi s1  [1024,1536)=lo s0  [1536,2048)=lo s1
//             within each 512: lane(= g*16 + code%16)*8 + i,  k-dim = s*32+g*8+i
//             +1 uninitialized guard tile (prefetch target at t=NT-1, never used)

__global__ __launch_bounds__(64) void prep_codebook(
    const float* __restrict__ w, float* __restrict__ wn,
    float* __restrict__ msw, _Float16* __restrict__ wf)
{
    int k = blockIdx.x;
    int d = threadIdx.x;
    float v = w[k * DIM + d];
    float sq = v * v;
    #pragma unroll
    for (int off = 32; off; off >>= 1) sq += __shfl_xor(sq, off, 64);
    float n = fmaxf(sqrtf(sq), EPSF);
    float o = v / n;
    wn[k * DIM + d] = o;
    float s2 = o * o;
    #pragma unroll
    for (int off = 32; off; off >>= 1) s2 += __shfl_xor(s2, off, 64);
    if (d == 0) msw[k] = -0.5f * s2;

    _Float16 hi = (_Float16)o;
    _Float16 lo = (_Float16)(o - (float)hi);
    // B fragment for 16x16x32: lane = g*16 + n holds k-dims s*32 + g*8 + i
    int t = k >> 4, nn = k & 15, s = d >> 5, g = (d >> 3) & 3, i = d & 7;
    size_t base = (size_t)t * 2048 + (size_t)s * 512 + (size_t)(g * 16 + nn) * 8 + i;
    wf[base] = hi;            // h = 0
    wf[base + 1024] = lo;     // h = 1
}

__global__ __launch_bounds__(256, 4) void vq_main_kernel(
    const float* __restrict__ x,
    const float* __restrict__ wn,
    const float* __restrict__ msw,
    const _Float16* __restrict__ wf,
    float* __restrict__ out_q,
    float* __restrict__ out_idx,
    float* __restrict__ partial)
{
    __shared__ float msw_lds[K_CODES + 16];   // +16 guard for t=NT-1 prefetch
    __shared__ int idx_lds[ROWS_PER_BLOCK];
    __shared__ float inv_lds[ROWS_PER_BLOCK];
    __shared__ float red[4];

    const int tid = threadIdx.x;
    const int wv = tid >> 6;
    const int lane = tid & 63;
    const int nidx = lane & 15;       // code-within-tile / x-row-within-rowtile
    const int g = lane >> 4;          // k-group
    const int block_row0 = blockIdx.x * ROWS_PER_BLOCK;

    // ---- prologue: 32 rows/wave (2 row-tiles of 16), normalize, hi/lo A-frags ----
    // A for 16x16x32: lane = g*16+m holds A[m][k = g*8+i] (+s*32 per kstep)
    f16x8 ah[2][2], al[2][2];
    #pragma unroll
    for (int rt = 0; rt < 2; ++rt) {
        const int arow = block_row0 + wv * 32 + rt * 16 + nidx;
        const float* xrow = x + (size_t)arow * DIM + g * 8;
        float xv[2][8];
        #pragma unroll
        for (int s = 0; s < 2; ++s) {
            float4 q0 = *(const float4*)(xrow + s * 32);
            float4 q1 = *(const float4*)(xrow + s * 32 + 4);
            xv[s][0] = q0.x; xv[s][1] = q0.y; xv[s][2] = q0.z; xv[s][3] = q0.w;
            xv[s][4] = q1.x; xv[s][5] = q1.y; xv[s][6] = q1.z; xv[s][7] = q1.w;
        }
        float ss = 0.f;
        #pragma unroll
        for (int s = 0; s < 2; ++s)
            #pragma unroll
            for (int i = 0; i < 8; ++i) ss += xv[s][i] * xv[s][i];
        ss += __shfl_xor(ss, 16, 64);  // sum across the 4 k-groups of this row
        ss += __shfl_xor(ss, 32, 64);
        float nrm = fmaxf(sqrtf(ss), EPSF);
        float inv = 1.0f / nrm;
        if (g == 0) inv_lds[wv * 32 + rt * 16 + nidx] = inv;
        #pragma unroll
        for (int s = 0; s < 2; ++s)
            #pragma unroll
            for (int i = 0; i < 8; ++i) {
                float v = xv[s][i] * inv;
                _Float16 hi = (_Float16)v;
                ah[rt][s][i] = hi;
                al[rt][s][i] = (_Float16)(v - (float)hi);
            }
    }

    // ---- stage msw into LDS (+zero guard) ----
    *(float4*)&msw_lds[tid * 4] = *(const float4*)(msw + tid * 4);
    if (tid < 4) {
        float4 z = {0.f, 0.f, 0.f, 0.f};
        *(float4*)&msw_lds[K_CODES + tid * 4] = z;
    }

    // ---- preload tile 0 (B-frags from global, mval from global) ----
    const _Float16* bbase = wf + (size_t)lane * 8;
    f16x8 cb0 = *(const f16x8*)(bbase);
    f16x8 cb1 = *(const f16x8*)(bbase + 512);
    f16x8 cb2 = *(const f16x8*)(bbase + 1024);
    f16x8 cb3 = *(const f16x8*)(bbase + 1536);
    float mval = msw[nidx];
    __syncthreads();

    float best[2][4];
    int bt[2][4];
    #pragma unroll
    for (int rt = 0; rt < 2; ++rt)
        #pragma unroll
        for (int r = 0; r < 4; ++r) { best[rt][r] = -3.4e38f; bt[rt][r] = 0; }

    // ---- main loop: 64 tiles, no barriers, depth-1 pipelined loads ----
    for (int t = 0; t < NT; ++t) {
        // issue tile t+1 loads first (guard tile makes t=NT-1 safe; unused)
        const _Float16* np = bbase + (size_t)(t + 1) * 2048;
        f16x8 nb0 = *(const f16x8*)(np);
        f16x8 nb1 = *(const f16x8*)(np + 512);
        f16x8 nb2 = *(const f16x8*)(np + 1024);
        f16x8 nb3 = *(const f16x8*)(np + 1536);
        float nmval = msw_lds[(t + 1) * 16 + nidx];

        f32x4 acc0 = {mval, mval, mval, mval};
        f32x4 acc1 = {mval, mval, mval, mval};
        __builtin_amdgcn_s_setprio(1);
        // 12 MFMA: two independent depth-6 chains (row-tile 0 / row-tile 1)
        acc0 = __builtin_amdgcn_mfma_f32_16x16x32_f16(ah[0][0], cb0, acc0, 0, 0, 0);
        acc1 = __builtin_amdgcn_mfma_f32_16x16x32_f16(ah[1][0], cb0, acc1, 0, 0, 0);
        acc0 = __builtin_amdgcn_mfma_f32_16x16x32_f16(ah[0][1], cb1, acc0, 0, 0, 0);
        acc1 = __builtin_amdgcn_mfma_f32_16x16x32_f16(ah[1][1], cb1, acc1, 0, 0, 0);
        acc0 = __builtin_amdgcn_mfma_f32_16x16x32_f16(al[0][0], cb0, acc0, 0, 0, 0);
        acc1 = __builtin_amdgcn_mfma_f32_16x16x32_f16(al[1][0], cb0, acc1, 0, 0, 0);
        acc0 = __builtin_amdgcn_mfma_f32_16x16x32_f16(al[0][1], cb1, acc0, 0, 0, 0);
        acc1 = __builtin_amdgcn_mfma_f32_16x16x32_f16(al[1][1], cb1, acc1, 0, 0, 0);
        acc0 = __builtin_amdgcn_mfma_f32_16x16x32_f16(ah[0][0], cb2, acc0, 0, 0, 0);
        acc1 = __builtin_amdgcn_mfma_f32_16x16x32_f16(ah[1][0], cb2, acc1, 0, 0, 0);
        acc0 = __builtin_amdgcn_mfma_f32_16x16x32_f16(ah[0][1], cb3, acc0, 0, 0, 0);
        acc1 = __builtin_amdgcn_mfma_f32_16x16x32_f16(ah[1][1], cb3, acc1, 0, 0, 0);
        __builtin_amdgcn_s_setprio(0);

        #pragma unroll
        for (int r = 0; r < 4; ++r) {
            if (acc0[r] > best[0][r]) { best[0][r] = acc0[r]; bt[0][r] = t; }
            if (acc1[r] > best[1][r]) { best[1][r] = acc1[r]; bt[1][r] = t; }
        }
        cb0 = nb0; cb1 = nb1; cb2 = nb2; cb3 = nb3; mval = nmval;
    }

    // ---- argmax reduce across the 16 lanes holding each row ----
    // C 16x16: col = lane&15 (code), row = (lane>>4)*4 + r
    #pragma unroll
    for (int rt = 0; rt < 2; ++rt)
        #pragma unroll
        for (int r = 0; r < 4; ++r) {
            float b = best[rt][r];
            int bi = bt[rt][r] * 16 + nidx;
            #pragma unroll
            for (int off = 1; off <= 8; off <<= 1) {
                float ob = __shfl_xor(b, off, 64);
                int oi = __shfl_xor(bi, off, 64);
                if (ob > b || (ob == b && oi < bi)) { b = ob; bi = oi; }
            }
            if (nidx == 0)
                idx_lds[wv * 32 + rt * 16 + g * 4 + r] = bi;
        }
    __syncthreads();

    // ---- epilogue: gather fp32 codebook row, write out, loss partial ----
    const int lr = tid >> 1;
    const int grow = block_row0 + lr;
    const int d0 = (tid & 1) * 32;
    const int ci = idx_lds[lr];
    const float invn = inv_lds[lr];
    const float4* xp = (const float4*)(x + (size_t)grow * DIM + d0);
    const float4* qp = (const float4*)(wn + (size_t)ci * DIM + d0);
    float4* op = (float4*)(out_q + (size_t)grow * DIM + d0);
    float ls = 0.f;
    #pragma unroll
    for (int i = 0; i < 8; ++i) {
        float4 qv = qp[i];
        float4 xv4 = xp[i];
        float e0 = qv.x - xv4.x * invn;
        float e1 = qv.y - xv4.y * invn;
        float e2 = qv.z - xv4.z * invn;
        float e3 = qv.w - xv4.w * invn;
        ls += e0 * e0 + e1 * e1 + e2 * e2 + e3 * e3;
        op[i] = qv;
    }
    if (!(tid & 1)) out_idx[grow] = (float)ci;

    float s = ls;
    #pragma unroll
    for (int off = 32; off; off >>= 1) s += __shfl_xor(s, off, 64);
    if (lane == 0) red[wv] = s;
    __syncthreads();
    if (tid == 0) partial[blockIdx.x] = (red[0] + red[1]) + (red[2] + red[3]);
}

__global__ __launch_bounds__(256) void finalize_kernel(
    const float* __restrict__ partial, float* __restrict__ loss_out)
{
    __shared__ float red[4];
    int t = threadIdx.x;
    float s = 0.f;
    #pragma unroll
    for (int i = 0; i < 8; ++i) s += partial[t * 8 + i];  // fixed order
    #pragma unroll
    for (int off = 32; off; off >>= 1) s += __shfl_xor(s, off, 64);
    if ((t & 63) == 0) red[t >> 6] = s;
    __syncthreads();
    if (t == 0)
        *loss_out = 1.25f * (((red[0] + red[1]) + (red[2] + red[3]))
                             / (float)((size_t)N_ROWS * DIM));
}

extern "C" void kernel_launch(void* const* d_in, const int* in_sizes, int n_in,
                              void* d_out, int out_size, void* d_ws, size_t ws_size,
                              hipStream_t stream) {
    const float* x = (const float*)d_in[0];   // [N, D]
    const float* w = (const float*)d_in[1];   // [K, D]
    float* out = (float*)d_out;
    float* ws = (float*)d_ws;

    float* wn      = ws;                                   // 65536 floats
    float* msw     = wn + (size_t)K_CODES * DIM;           // 1024 floats
    float* partial = msw + K_CODES;                        // 2048 floats
    _Float16* wf   = (_Float16*)(partial + 2048);          // 65*2048 halves (incl. guard)

    float* out_q    = out;                                 // [N*D]
    float* out_loss = out + (size_t)N_ROWS * DIM;          // [1]
    float* out_idx  = out_loss + 1;                        // [N]

    prep_codebook<<<K_CODES, 64, 0, stream>>>(w, wn, msw, wf);
    vq_main_kernel<<<N_ROWS / ROWS_PER_BLOCK, 256, 0, stream>>>(
        x, wn, msw, wf, out_q, out_idx, partial);
    finalize_kernel<<<1, 256, 0, stream>>>(partial, out_loss);
}